// Round 1
// baseline (129.689 us; speedup 1.0000x reference)
//
#include <hip/hip_runtime.h>
#include <math.h>

#define B_    8
#define N_    9225
#define M_    4096
#define K_    32
#define HID_  64
#define DOUT_ 16

// One lane per (row=b*M+m, k): evaluates the whole MLP for one neighbor.
// 32 lanes (half-wave) cover the K=32 neighbors of one row; channel-halving
// butterfly reduces the 16 output channels across those 32 lanes.
// All weight accesses are wave-uniform -> scalar loads (SGPR operands in FMA).
__global__ __launch_bounds__(256) void it_kernel(
    const float* __restrict__ y,
    const float* __restrict__ x,
    const float* __restrict__ f_y,
    const float* __restrict__ weights,
    const float* __restrict__ W1,   // [4][64] row-major
    const float* __restrict__ b1,   // [64]
    const float* __restrict__ W2,   // [64][16] row-major
    const float* __restrict__ b2,   // [16]
    const int*   __restrict__ nbr,  // [B][M][K] int32
    float*       __restrict__ out)  // [B][M][16]
{
    const int tid  = threadIdx.x;
    const int lane = tid & 63;
    const int k    = lane & 31;
    const int row  = blockIdx.x * 8 + (tid >> 5);   // b*M + m
    const int b    = row >> 12;                     // M = 4096
    const int m    = row & (M_ - 1);

    // ---- gathers ----
    const int idx_raw = nbr[(size_t)row * K_ + k];
    const bool valid  = idx_raw >= 0;
    const int  i0     = valid ? idx_raw : 0;

    const size_t bn = (size_t)b * N_ + i0;
    const float2 yv = *(const float2*)(y + bn * 2);
    const float  wn = weights[bn];
    const float  scale = valid ? wn : 0.0f;
    const float4 f0 = *(const float4*)(f_y + bn * 16);
    const float4 f1 = *(const float4*)(f_y + bn * 16 + 4);
    const float4 f2 = *(const float4*)(f_y + bn * 16 + 8);
    const float4 f3 = *(const float4*)(f_y + bn * 16 + 12);
    const float2 xv = *(const float2*)(x + ((size_t)b * M_ + m) * 2);

    // ---- MLP: h = gelu(agg @ W1 + b1); kv = h @ W2 ----
    float kv[DOUT_];
    #pragma unroll
    for (int c = 0; c < DOUT_; ++c) kv[c] = 0.0f;

    #pragma unroll 4
    for (int j = 0; j < HID_; ++j) {
        float hin = b1[j];
        hin = fmaf(yv.x, W1[j],       hin);
        hin = fmaf(yv.y, W1[64 + j],  hin);
        hin = fmaf(xv.x, W1[128 + j], hin);
        hin = fmaf(xv.y, W1[192 + j], hin);
        const float h = 0.5f * hin * (1.0f + erff(hin * 0.70710678118654752f));
        #pragma unroll
        for (int c = 0; c < DOUT_; ++c)
            kv[c] = fmaf(h, W2[j * DOUT_ + c], kv[c]);
    }

    // ---- epilogue: (kv + b2) * f * w * valid ----
    const float fv[DOUT_] = { f0.x, f0.y, f0.z, f0.w,
                              f1.x, f1.y, f1.z, f1.w,
                              f2.x, f2.y, f2.z, f2.w,
                              f3.x, f3.y, f3.z, f3.w };
    #pragma unroll
    for (int c = 0; c < DOUT_; ++c)
        kv[c] = (kv[c] + b2[c]) * fv[c] * scale;

    // ---- channel-halving butterfly over the 32 k-lanes ----
    const int bit4 = (lane >> 4) & 1;
    float r8[8];
    #pragma unroll
    for (int i = 0; i < 8; ++i) {
        const float keep = bit4 ? kv[8 + i] : kv[i];
        const float send = bit4 ? kv[i]     : kv[8 + i];
        r8[i] = keep + __shfl_xor(send, 16, 64);
    }
    const int bit3 = (lane >> 3) & 1;
    float r4[4];
    #pragma unroll
    for (int i = 0; i < 4; ++i) {
        const float keep = bit3 ? r8[4 + i] : r8[i];
        const float send = bit3 ? r8[i]     : r8[4 + i];
        r4[i] = keep + __shfl_xor(send, 8, 64);
    }
    const int bit2 = (lane >> 2) & 1;
    float r2[2];
    #pragma unroll
    for (int i = 0; i < 2; ++i) {
        const float keep = bit2 ? r4[2 + i] : r4[i];
        const float send = bit2 ? r4[i]     : r4[2 + i];
        r2[i] = keep + __shfl_xor(send, 4, 64);
    }
    const int bit1 = (lane >> 1) & 1;
    {
        const float keep = bit1 ? r2[1] : r2[0];
        const float send = bit1 ? r2[0] : r2[1];
        const float r1   = keep + __shfl_xor(send, 2, 64);
        const float tot  = r1 + __shfl_xor(r1, 1, 64);
        if ((lane & 1) == 0)
            out[(size_t)row * DOUT_ + ((lane >> 1) & 15)] = tot;
    }
}

extern "C" void kernel_launch(void* const* d_in, const int* in_sizes, int n_in,
                              void* d_out, int out_size, void* d_ws, size_t ws_size,
                              hipStream_t stream) {
    const float* y   = (const float*)d_in[0];
    const float* x   = (const float*)d_in[1];
    const float* f_y = (const float*)d_in[2];
    const float* w   = (const float*)d_in[3];
    const float* W1  = (const float*)d_in[4];
    const float* b1  = (const float*)d_in[5];
    const float* W2  = (const float*)d_in[6];
    const float* b2  = (const float*)d_in[7];
    const int*   nbr = (const int*)d_in[8];
    float* out = (float*)d_out;

    dim3 grid(B_ * M_ / 8), block(256);
    hipLaunchKernelGGL(it_kernel, grid, block, 0, stream,
                       y, x, f_y, w, W1, b1, W2, b2, nbr, out);
}

// Round 2
// 110.500 us; speedup vs baseline: 1.1737x; 1.1737x over previous
//
#include <hip/hip_runtime.h>
#include <hip/hip_bf16.h>
#include <math.h>

#define B_    8
#define N_    9225
#define M_    4096
#define K_    32
#define HID_  64
#define DOUT_ 16
#define RPW   4   // rows per wave

typedef __attribute__((ext_vector_type(8))) short short8;
typedef __attribute__((ext_vector_type(4))) float floatx4;

static __device__ __forceinline__ short f2bf(float f) {
    __hip_bfloat16 h = __float2bfloat16(f);
    return __builtin_bit_cast(short, h);
}

// Wave-autonomous kernel: one wave owns RPW rows; per row, 32 neighbors are
// processed as two halves of 16 (n = lane&15). Each lane computes h for its
// neighbor at j = chunk*32 + quad*8 + jj (exactly the MFMA B-fragment slots),
// then C' = W2^T (A-frag) x h^T (B-frag) puts channel q*4+reg in regs with
// col = this lane's own neighbor -> lane-local f*s epilogue, shfl butterfly.
__global__ __launch_bounds__(256) void it_kernel(
    const float* __restrict__ y,
    const float* __restrict__ x,
    const float* __restrict__ f_y,
    const float* __restrict__ weights,
    const float* __restrict__ W1,   // [4][64] row-major
    const float* __restrict__ b1,   // [64]
    const float* __restrict__ W2,   // [64][16] row-major
    const float* __restrict__ b2,   // [16]
    const int*   __restrict__ nbr,  // [B][M][K] int32
    float*       __restrict__ out)  // [B][M][16]
{
    const int tid  = threadIdx.x;
    const int lane = tid & 63;
    const int q    = lane >> 4;    // quad 0..3
    const int nlo  = lane & 15;    // neighbor-within-half; also c for W2 A-frag
    const int wave = blockIdx.x * 4 + (tid >> 6);

    // ---- per-lane W1/b1 register slices for j in {ch*32 + q*8 + jj} ----
    float w1r[2][4][8];
    float b1r[2][8];
    #pragma unroll
    for (int ch = 0; ch < 2; ++ch) {
        #pragma unroll
        for (int i = 0; i < 4; ++i) {
            const floatx4 a0 = *(const floatx4*)(W1 + i*64 + ch*32 + q*8);
            const floatx4 a1 = *(const floatx4*)(W1 + i*64 + ch*32 + q*8 + 4);
            #pragma unroll
            for (int jj = 0; jj < 4; ++jj) { w1r[ch][i][jj] = a0[jj]; w1r[ch][i][4+jj] = a1[jj]; }
        }
        const floatx4 c0 = *(const floatx4*)(b1 + ch*32 + q*8);
        const floatx4 c1 = *(const floatx4*)(b1 + ch*32 + q*8 + 4);
        #pragma unroll
        for (int jj = 0; jj < 4; ++jj) { b1r[ch][jj] = c0[jj]; b1r[ch][4+jj] = c1[jj]; }
    }

    // ---- W2 A-fragment: lane holds A[m=c=nlo][k=q*8+jj] = W2[j][nlo], bf16 ----
    short8 w2f[2];
    #pragma unroll
    for (int ch = 0; ch < 2; ++ch)
        #pragma unroll
        for (int jj = 0; jj < 8; ++jj)
            w2f[ch][jj] = f2bf(W2[(ch*32 + q*8 + jj) * DOUT_ + nlo]);

    const floatx4 b2v = *(const floatx4*)(b2 + q*4);

    for (int it = 0; it < RPW; ++it) {
        const int row = wave * RPW + it;         // b*M + m
        const int b   = row >> 12;               // M = 4096
        const long bbase = (long)b * N_;
        const float2 xv = *(const float2*)(x + (size_t)row * 2);

        // ---- gathers for both halves (hoisted for latency hiding) ----
        float  s[2]; float2 yv[2]; floatx4 fv[2];
        #pragma unroll
        for (int h = 0; h < 2; ++h) {
            const int  raw   = nbr[(size_t)row * K_ + h*16 + nlo];
            const bool valid = raw >= 0;
            const long bn    = bbase + (valid ? raw : 0);
            yv[h] = *(const float2*)(y + bn * 2);
            s[h]  = valid ? weights[bn] : 0.0f;
            fv[h] = *(const floatx4*)(f_y + bn * 16 + q*4);
        }

        float partial[4] = {0.f, 0.f, 0.f, 0.f};
        #pragma unroll
        for (int h = 0; h < 2; ++h) {
            short8 hf[2];
            #pragma unroll
            for (int ch = 0; ch < 2; ++ch) {
                #pragma unroll
                for (int jj = 0; jj < 8; ++jj) {
                    float hin = b1r[ch][jj];
                    hin = fmaf(yv[h].x, w1r[ch][0][jj], hin);
                    hin = fmaf(yv[h].y, w1r[ch][1][jj], hin);
                    hin = fmaf(xv.x,    w1r[ch][2][jj], hin);
                    hin = fmaf(xv.y,    w1r[ch][3][jj], hin);
                    // gelu(x) ~ x - x * 1/(1+exp(1.5957691*x*(1+0.044715*x^2)))
                    const float inner = fmaf(hin * hin, 0.044715f, 1.0f);
                    const float e = __expf(hin * inner * 1.59576912f);
                    const float r = __builtin_amdgcn_rcpf(1.0f + e);
                    const float g = fmaf(-hin, r, hin);
                    hf[ch][jj] = f2bf(g);
                }
            }
            floatx4 acc = {0.f, 0.f, 0.f, 0.f};
            acc = __builtin_amdgcn_mfma_f32_16x16x32_bf16(w2f[0], hf[0], acc, 0, 0, 0);
            acc = __builtin_amdgcn_mfma_f32_16x16x32_bf16(w2f[1], hf[1], acc, 0, 0, 0);
            #pragma unroll
            for (int r4 = 0; r4 < 4; ++r4)
                partial[r4] = fmaf(acc[r4] + b2v[r4], fv[h][r4] * s[h], partial[r4]);
        }

        // ---- sum over the 16 neighbors (low 4 lane bits) ----
        #pragma unroll
        for (int mask = 1; mask <= 8; mask <<= 1)
            #pragma unroll
            for (int r4 = 0; r4 < 4; ++r4)
                partial[r4] += __shfl_xor(partial[r4], mask, 64);

        if (nlo == 0) {
            floatx4 o = {partial[0], partial[1], partial[2], partial[3]};
            *(floatx4*)(out + (size_t)row * DOUT_ + q*4) = o;
        }
    }
}

extern "C" void kernel_launch(void* const* d_in, const int* in_sizes, int n_in,
                              void* d_out, int out_size, void* d_ws, size_t ws_size,
                              hipStream_t stream) {
    const float* y   = (const float*)d_in[0];
    const float* x   = (const float*)d_in[1];
    const float* f_y = (const float*)d_in[2];
    const float* w   = (const float*)d_in[3];
    const float* W1  = (const float*)d_in[4];
    const float* b1  = (const float*)d_in[5];
    const float* W2  = (const float*)d_in[6];
    const float* b2  = (const float*)d_in[7];
    const int*   nbr = (const int*)d_in[8];
    float* out = (float*)d_out;

    // 32768 rows / (4 waves * RPW rows) = 2048 blocks
    dim3 grid(B_ * M_ / (4 * RPW)), block(256);
    hipLaunchKernelGGL(it_kernel, grid, block, 0, stream,
                       y, x, f_y, w, W1, b1, W2, b2, nbr, out);
}

// Round 3
// 109.056 us; speedup vs baseline: 1.1892x; 1.0132x over previous
//
#include <hip/hip_runtime.h>
#include <hip/hip_bf16.h>
#include <math.h>

#define B_    8
#define N_    9225
#define M_    4096
#define K_    32
#define HID_  64
#define DOUT_ 16
#define RPW   4   // rows per wave

typedef __attribute__((ext_vector_type(8))) short short8;
typedef __attribute__((ext_vector_type(4))) float floatx4;
typedef __attribute__((ext_vector_type(2))) float f32x2;

static __device__ __forceinline__ short f2bf(float f) {
    __hip_bfloat16 h = __float2bfloat16(f);
    return __builtin_bit_cast(short, h);
}
static __device__ __forceinline__ f32x2 splat2(float v) { return (f32x2){v, v}; }

// Sum over each 16-lane DPP row via row_shr tree; lane (row*16+15) holds the sum.
static __device__ __forceinline__ float row16_sum(float v) {
    int t;
    t = __builtin_amdgcn_update_dpp(0, __builtin_bit_cast(int, v), 0x111, 0xF, 0xF, true);
    v += __builtin_bit_cast(float, t);
    t = __builtin_amdgcn_update_dpp(0, __builtin_bit_cast(int, v), 0x112, 0xF, 0xF, true);
    v += __builtin_bit_cast(float, t);
    t = __builtin_amdgcn_update_dpp(0, __builtin_bit_cast(int, v), 0x114, 0xF, 0xF, true);
    v += __builtin_bit_cast(float, t);
    t = __builtin_amdgcn_update_dpp(0, __builtin_bit_cast(int, v), 0x118, 0xF, 0xF, true);
    v += __builtin_bit_cast(float, t);
    return v;
}

// Wave-autonomous: one wave owns RPW rows; 32 neighbors as two halves of 16
// (n = lane&15). Lane computes h for j = ch*32 + q*8 + jj (the MFMA B-frag
// slots); C' = W2^T x h^T puts channel q*4+reg in regs with col = own
// neighbor -> lane-local f*w epilogue, DPP row-sum, lane15 stores.
__global__ __launch_bounds__(256) void it_kernel(
    const float* __restrict__ y,
    const float* __restrict__ x,
    const float* __restrict__ f_y,
    const float* __restrict__ weights,
    const float* __restrict__ W1,   // [4][64] row-major
    const float* __restrict__ b1,   // [64]
    const float* __restrict__ W2,   // [64][16] row-major
    const float* __restrict__ b2,   // [16]
    const int*   __restrict__ nbr,  // [B][M][K] int32
    float*       __restrict__ out)  // [B][M][16]
{
    const int tid  = threadIdx.x;
    const int lane = tid & 63;
    const int q    = lane >> 4;    // quad 0..3
    const int nlo  = lane & 15;    // neighbor-within-half; also c for W2 A-frag
    const int wave = blockIdx.x * 4 + (tid >> 6);

    // ---- per-lane W1/b1 register slices (float2-packed) ----
    f32x2 w1r[2][4][4];   // [chunk][input dim][jj pair]
    f32x2 b1r[2][4];
    #pragma unroll
    for (int ch = 0; ch < 2; ++ch) {
        #pragma unroll
        for (int i = 0; i < 4; ++i) {
            const floatx4 a0 = *(const floatx4*)(W1 + i*64 + ch*32 + q*8);
            const floatx4 a1 = *(const floatx4*)(W1 + i*64 + ch*32 + q*8 + 4);
            w1r[ch][i][0] = (f32x2){a0[0], a0[1]};
            w1r[ch][i][1] = (f32x2){a0[2], a0[3]};
            w1r[ch][i][2] = (f32x2){a1[0], a1[1]};
            w1r[ch][i][3] = (f32x2){a1[2], a1[3]};
        }
        const floatx4 c0 = *(const floatx4*)(b1 + ch*32 + q*8);
        const floatx4 c1 = *(const floatx4*)(b1 + ch*32 + q*8 + 4);
        b1r[ch][0] = (f32x2){c0[0], c0[1]};
        b1r[ch][1] = (f32x2){c0[2], c0[3]};
        b1r[ch][2] = (f32x2){c1[0], c1[1]};
        b1r[ch][3] = (f32x2){c1[2], c1[3]};
    }

    // ---- W2 A-fragment: lane holds A[m=c=nlo][k=q*8+jj] = W2[j][nlo], bf16 ----
    short8 w2f[2];
    #pragma unroll
    for (int ch = 0; ch < 2; ++ch)
        #pragma unroll
        for (int jj = 0; jj < 8; ++jj)
            w2f[ch][jj] = f2bf(W2[(ch*32 + q*8 + jj) * DOUT_ + nlo]);

    const floatx4 b2v = *(const floatx4*)(b2 + q*4);

    for (int it = 0; it < RPW; ++it) {
        const int row = wave * RPW + it;         // b*M + m
        const int b   = row >> 12;               // M = 4096
        const long bbase = (long)b * N_;
        const float2 xv = *(const float2*)(x + (size_t)row * 2);

        // ---- gathers for both halves (hoisted for latency hiding) ----
        float  s[2]; float2 yv[2]; floatx4 fv[2];
        #pragma unroll
        for (int h = 0; h < 2; ++h) {
            const int  raw   = nbr[(size_t)row * K_ + h*16 + nlo];
            const bool valid = raw >= 0;
            const long bn    = bbase + (valid ? raw : 0);
            yv[h] = *(const float2*)(y + bn * 2);
            s[h]  = valid ? weights[bn] : 0.0f;
            fv[h] = *(const floatx4*)(f_y + bn * 16 + q*4);
        }

        float partial[4] = {0.f, 0.f, 0.f, 0.f};
        #pragma unroll
        for (int h = 0; h < 2; ++h) {
            short8 hf[2];
            #pragma unroll
            for (int ch = 0; ch < 2; ++ch) {
                #pragma unroll
                for (int p = 0; p < 4; ++p) {
                    f32x2 hin = b1r[ch][p];
                    hin = __builtin_elementwise_fma(splat2(yv[h].x), w1r[ch][0][p], hin);
                    hin = __builtin_elementwise_fma(splat2(yv[h].y), w1r[ch][1][p], hin);
                    hin = __builtin_elementwise_fma(splat2(xv.x),    w1r[ch][2][p], hin);
                    hin = __builtin_elementwise_fma(splat2(xv.y),    w1r[ch][3][p], hin);
                    // gelu(x) ~ x - x/(1+exp(x*(1.5957691 + 0.07135481*x^2)))
                    const f32x2 hsq = hin * hin;
                    const f32x2 tt  = __builtin_elementwise_fma(hsq, splat2(0.07135481f),
                                                                splat2(1.59576912f));
                    const f32x2 z   = hin * tt;
                    const float e0  = __expf(z[0]);
                    const float e1  = __expf(z[1]);
                    const f32x2 r   = { __builtin_amdgcn_rcpf(1.0f + e0),
                                        __builtin_amdgcn_rcpf(1.0f + e1) };
                    const f32x2 g   = __builtin_elementwise_fma(-hin, r, hin);
                    hf[ch][2*p]     = f2bf(g[0]);
                    hf[ch][2*p + 1] = f2bf(g[1]);
                }
            }
            floatx4 acc = {0.f, 0.f, 0.f, 0.f};
            acc = __builtin_amdgcn_mfma_f32_16x16x32_bf16(w2f[0], hf[0], acc, 0, 0, 0);
            acc = __builtin_amdgcn_mfma_f32_16x16x32_bf16(w2f[1], hf[1], acc, 0, 0, 0);
            #pragma unroll
            for (int r4 = 0; r4 < 4; ++r4)
                partial[r4] = fmaf(acc[r4] + b2v[r4], fv[h][r4] * s[h], partial[r4]);
        }

        // ---- sum over the 16 neighbors via DPP row_shr tree ----
        #pragma unroll
        for (int r4 = 0; r4 < 4; ++r4)
            partial[r4] = row16_sum(partial[r4]);

        if (nlo == 15) {
            floatx4 o = {partial[0], partial[1], partial[2], partial[3]};
            *(floatx4*)(out + (size_t)row * DOUT_ + q*4) = o;
        }
    }
}

extern "C" void kernel_launch(void* const* d_in, const int* in_sizes, int n_in,
                              void* d_out, int out_size, void* d_ws, size_t ws_size,
                              hipStream_t stream) {
    const float* y   = (const float*)d_in[0];
    const float* x   = (const float*)d_in[1];
    const float* f_y = (const float*)d_in[2];
    const float* w   = (const float*)d_in[3];
    const float* W1  = (const float*)d_in[4];
    const float* b1  = (const float*)d_in[5];
    const float* W2  = (const float*)d_in[6];
    const float* b2  = (const float*)d_in[7];
    const int*   nbr = (const int*)d_in[8];
    float* out = (float*)d_out;

    // 32768 rows / (4 waves * RPW rows) = 2048 blocks
    dim3 grid(B_ * M_ / (4 * RPW)), block(256);
    hipLaunchKernelGGL(it_kernel, grid, block, 0, stream,
                       y, x, f_y, w, W1, b1, W2, b2, nbr, out);
}

// Round 4
// 108.993 us; speedup vs baseline: 1.1899x; 1.0006x over previous
//
#include <hip/hip_runtime.h>
#include <hip/hip_bf16.h>
#include <math.h>

#define B_    8
#define N_    9225
#define M_    4096
#define K_    32
#define HID_  64
#define DOUT_ 16
#define RPW   2   // rows per wave

typedef __attribute__((ext_vector_type(8))) short short8;
typedef __attribute__((ext_vector_type(4))) float floatx4;
typedef __attribute__((ext_vector_type(2))) float f32x2;

static __device__ __forceinline__ short f2bf(float f) {
    __hip_bfloat16 h = __float2bfloat16(f);
    return __builtin_bit_cast(short, h);
}
static __device__ __forceinline__ f32x2 splat2(float v) { return (f32x2){v, v}; }

// Sum over each 16-lane DPP row via row_shr tree; lane (row*16+15) holds the sum.
static __device__ __forceinline__ float row16_sum(float v) {
    int t;
    t = __builtin_amdgcn_update_dpp(0, __builtin_bit_cast(int, v), 0x111, 0xF, 0xF, true);
    v += __builtin_bit_cast(float, t);
    t = __builtin_amdgcn_update_dpp(0, __builtin_bit_cast(int, v), 0x112, 0xF, 0xF, true);
    v += __builtin_bit_cast(float, t);
    t = __builtin_amdgcn_update_dpp(0, __builtin_bit_cast(int, v), 0x114, 0xF, 0xF, true);
    v += __builtin_bit_cast(float, t);
    t = __builtin_amdgcn_update_dpp(0, __builtin_bit_cast(int, v), 0x118, 0xF, 0xF, true);
    v += __builtin_bit_cast(float, t);
    return v;
}

// gelu(x) ~ 0.5*x*(1 + tanh(z)), z = x*(0.79788456 + 0.035677408*x^2),
// tanh via exact Pade(5,4): z*(945 + 105u + u^2) / (945 + 420u + 15u^2), u=z^2,
// clamped to [-1,1]. Max |h-err| ~2e-3 (under bf16 rounding). No v_exp.
static __device__ __forceinline__ f32x2 gelu2(f32x2 x) {
    const f32x2 xsq = x * x;
    const f32x2 t   = __builtin_elementwise_fma(xsq, splat2(0.035677408f), splat2(0.79788456f));
    const f32x2 z   = x * t;
    const f32x2 u   = z * z;
    const f32x2 a   = u + splat2(105.0f);
    const f32x2 nin = __builtin_elementwise_fma(u, a, splat2(945.0f));
    const f32x2 num = z * nin;
    const f32x2 bq  = __builtin_elementwise_fma(u, splat2(15.0f), splat2(420.0f));
    const f32x2 den = __builtin_elementwise_fma(u, bq, splat2(945.0f));
    const f32x2 r   = { __builtin_amdgcn_rcpf(den[0]), __builtin_amdgcn_rcpf(den[1]) };
    f32x2 th = num * r;
    th = __builtin_elementwise_min(__builtin_elementwise_max(th, splat2(-1.0f)), splat2(1.0f));
    const f32x2 hx = x * splat2(0.5f);
    return __builtin_elementwise_fma(hx, th, hx);
}

// Wave-autonomous: one wave owns RPW rows; 32 neighbors as two halves of 16
// (n = lane&15). Lane computes h for j = ch*32 + q*8 + jj (the MFMA B-frag
// slots); C' = W2^T x h^T puts channel q*4+reg in regs with col = own
// neighbor -> lane-local f*w epilogue, DPP row-sum, lane15 stores.
__global__ __launch_bounds__(256) void it_kernel(
    const float* __restrict__ y,
    const float* __restrict__ x,
    const float* __restrict__ f_y,
    const float* __restrict__ weights,
    const float* __restrict__ W1,   // [4][64] row-major
    const float* __restrict__ b1,   // [64]
    const float* __restrict__ W2,   // [64][16] row-major
    const float* __restrict__ b2,   // [16]
    const int*   __restrict__ nbr,  // [B][M][K] int32
    float*       __restrict__ out)  // [B][M][16]
{
    const int tid  = threadIdx.x;
    const int lane = tid & 63;
    const int q    = lane >> 4;    // quad 0..3
    const int nlo  = lane & 15;    // neighbor-within-half; also c for W2 A-frag
    const int wave = blockIdx.x * 4 + (tid >> 6);
    const int row0 = wave * RPW;

    // ---- per-lane W1/b1 register slices (float2-packed) ----
    f32x2 w1r[2][4][4];   // [chunk][input dim][jj pair]
    f32x2 b1r[2][4];
    #pragma unroll
    for (int ch = 0; ch < 2; ++ch) {
        #pragma unroll
        for (int i = 0; i < 4; ++i) {
            const floatx4 a0 = *(const floatx4*)(W1 + i*64 + ch*32 + q*8);
            const floatx4 a1 = *(const floatx4*)(W1 + i*64 + ch*32 + q*8 + 4);
            w1r[ch][i][0] = (f32x2){a0[0], a0[1]};
            w1r[ch][i][1] = (f32x2){a0[2], a0[3]};
            w1r[ch][i][2] = (f32x2){a1[0], a1[1]};
            w1r[ch][i][3] = (f32x2){a1[2], a1[3]};
        }
        const floatx4 c0 = *(const floatx4*)(b1 + ch*32 + q*8);
        const floatx4 c1 = *(const floatx4*)(b1 + ch*32 + q*8 + 4);
        b1r[ch][0] = (f32x2){c0[0], c0[1]};
        b1r[ch][1] = (f32x2){c0[2], c0[3]};
        b1r[ch][2] = (f32x2){c1[0], c1[1]};
        b1r[ch][3] = (f32x2){c1[2], c1[3]};
    }

    // ---- W2 A-fragment: lane holds A[m=c=nlo][k=q*8+jj] = W2[j][nlo], bf16 ----
    short8 w2f[2];
    #pragma unroll
    for (int ch = 0; ch < 2; ++ch)
        #pragma unroll
        for (int jj = 0; jj < 8; ++jj)
            w2f[ch][jj] = f2bf(W2[(ch*32 + q*8 + jj) * DOUT_ + nlo]);

    const floatx4 b2v = *(const floatx4*)(b2 + q*4);

    // ---- hoist ALL rows' gathers up front (keep loads in flight) ----
    float  s[RPW][2]; float2 yv[RPW][2]; floatx4 fv[RPW][2]; float2 xv[RPW];
    #pragma unroll
    for (int it = 0; it < RPW; ++it) {
        const int row = row0 + it;               // b*M + m
        const int b   = row >> 12;               // M = 4096
        const long bbase = (long)b * N_;
        xv[it] = *(const float2*)(x + (size_t)row * 2);
        #pragma unroll
        for (int h = 0; h < 2; ++h) {
            const int  raw   = nbr[(size_t)row * K_ + h*16 + nlo];
            const bool valid = raw >= 0;
            const long bn    = bbase + (valid ? raw : 0);
            yv[it][h] = *(const float2*)(y + bn * 2);
            s[it][h]  = valid ? weights[bn] : 0.0f;
            fv[it][h] = *(const floatx4*)(f_y + bn * 16 + q*4);
        }
    }

    #pragma unroll
    for (int it = 0; it < RPW; ++it) {
        const int row = row0 + it;
        float partial[4] = {0.f, 0.f, 0.f, 0.f};
        #pragma unroll
        for (int h = 0; h < 2; ++h) {
            short8 hf[2];
            #pragma unroll
            for (int ch = 0; ch < 2; ++ch) {
                #pragma unroll
                for (int p = 0; p < 4; ++p) {
                    f32x2 hin = b1r[ch][p];
                    hin = __builtin_elementwise_fma(splat2(yv[it][h].x), w1r[ch][0][p], hin);
                    hin = __builtin_elementwise_fma(splat2(yv[it][h].y), w1r[ch][1][p], hin);
                    hin = __builtin_elementwise_fma(splat2(xv[it].x),    w1r[ch][2][p], hin);
                    hin = __builtin_elementwise_fma(splat2(xv[it].y),    w1r[ch][3][p], hin);
                    const f32x2 g = gelu2(hin);
                    hf[ch][2*p]     = f2bf(g[0]);
                    hf[ch][2*p + 1] = f2bf(g[1]);
                }
            }
            floatx4 acc = {0.f, 0.f, 0.f, 0.f};
            acc = __builtin_amdgcn_mfma_f32_16x16x32_bf16(w2f[0], hf[0], acc, 0, 0, 0);
            acc = __builtin_amdgcn_mfma_f32_16x16x32_bf16(w2f[1], hf[1], acc, 0, 0, 0);
            #pragma unroll
            for (int r4 = 0; r4 < 4; ++r4)
                partial[r4] = fmaf(acc[r4] + b2v[r4], fv[it][h][r4] * s[it][h], partial[r4]);
        }

        // ---- sum over the 16 neighbors via DPP row_shr tree ----
        #pragma unroll
        for (int r4 = 0; r4 < 4; ++r4)
            partial[r4] = row16_sum(partial[r4]);

        if (nlo == 15) {
            floatx4 o = {partial[0], partial[1], partial[2], partial[3]};
            *(floatx4*)(out + (size_t)row * DOUT_ + q*4) = o;
        }
    }
}

extern "C" void kernel_launch(void* const* d_in, const int* in_sizes, int n_in,
                              void* d_out, int out_size, void* d_ws, size_t ws_size,
                              hipStream_t stream) {
    const float* y   = (const float*)d_in[0];
    const float* x   = (const float*)d_in[1];
    const float* f_y = (const float*)d_in[2];
    const float* w   = (const float*)d_in[3];
    const float* W1  = (const float*)d_in[4];
    const float* b1  = (const float*)d_in[5];
    const float* W2  = (const float*)d_in[6];
    const float* b2  = (const float*)d_in[7];
    const int*   nbr = (const int*)d_in[8];
    float* out = (float*)d_out;

    // 32768 rows / (4 waves * RPW rows) = 4096 blocks
    dim3 grid(B_ * M_ / (4 * RPW)), block(256);
    hipLaunchKernelGGL(it_kernel, grid, block, 0, stream,
                       y, x, f_y, w, W1, b1, W2, b2, nbr, out);
}

// Round 5
// 107.237 us; speedup vs baseline: 1.2094x; 1.0164x over previous
//
#include <hip/hip_runtime.h>
#include <hip/hip_bf16.h>
#include <math.h>

#define B_    8
#define N_    9225
#define M_    4096
#define K_    32
#define HID_  64
#define DOUT_ 16
#define RPW   2   // rows per wave (fixed: dedup mapping uses 64 lanes = 2 rows x 32 nbrs)

typedef __attribute__((ext_vector_type(8))) short short8;
typedef __attribute__((ext_vector_type(4))) float floatx4;
typedef __attribute__((ext_vector_type(2))) float f32x2;

static __device__ __forceinline__ short f2bf(float f) {
    __hip_bfloat16 h = __float2bfloat16(f);
    return __builtin_bit_cast(short, h);
}
static __device__ __forceinline__ f32x2 splat2(float v) { return (f32x2){v, v}; }
static __device__ __forceinline__ int bpermi(int src_bytes, int v) {
    return __builtin_amdgcn_ds_bpermute(src_bytes, v);
}
static __device__ __forceinline__ float bpermf(int src_bytes, float v) {
    return __builtin_bit_cast(float,
        __builtin_amdgcn_ds_bpermute(src_bytes, __builtin_bit_cast(int, v)));
}

// Sum over each 16-lane DPP row via row_shr tree; lane (row*16+15) holds the sum.
static __device__ __forceinline__ float row16_sum(float v) {
    int t;
    t = __builtin_amdgcn_update_dpp(0, __builtin_bit_cast(int, v), 0x111, 0xF, 0xF, true);
    v += __builtin_bit_cast(float, t);
    t = __builtin_amdgcn_update_dpp(0, __builtin_bit_cast(int, v), 0x112, 0xF, 0xF, true);
    v += __builtin_bit_cast(float, t);
    t = __builtin_amdgcn_update_dpp(0, __builtin_bit_cast(int, v), 0x114, 0xF, 0xF, true);
    v += __builtin_bit_cast(float, t);
    t = __builtin_amdgcn_update_dpp(0, __builtin_bit_cast(int, v), 0x118, 0xF, 0xF, true);
    v += __builtin_bit_cast(float, t);
    return v;
}

// gelu(x) ~ 0.5*x*(1 + tanh(z)), z = x*(0.79788456 + 0.035677408*x^2),
// tanh via Pade(5,4), clamped to [-1,1]. No v_exp.
static __device__ __forceinline__ f32x2 gelu2(f32x2 x) {
    const f32x2 xsq = x * x;
    const f32x2 t   = __builtin_elementwise_fma(xsq, splat2(0.035677408f), splat2(0.79788456f));
    const f32x2 z   = x * t;
    const f32x2 u   = z * z;
    const f32x2 a   = u + splat2(105.0f);
    const f32x2 nin = __builtin_elementwise_fma(u, a, splat2(945.0f));
    const f32x2 num = z * nin;
    const f32x2 bq  = __builtin_elementwise_fma(u, splat2(15.0f), splat2(420.0f));
    const f32x2 den = __builtin_elementwise_fma(u, bq, splat2(945.0f));
    const f32x2 r   = { __builtin_amdgcn_rcpf(den[0]), __builtin_amdgcn_rcpf(den[1]) };
    f32x2 th = num * r;
    th = __builtin_elementwise_min(__builtin_elementwise_max(th, splat2(-1.0f)), splat2(1.0f));
    const f32x2 hx = x * splat2(0.5f);
    return __builtin_elementwise_fma(hx, th, hx);
}

// Wave owns 2 rows. GATHER phase: lane g = (row g>>5, nbr g&31) loads
// nbr/y/weights exactly once (no cross-quad duplication); ds_bpermute
// redistributes bn / y / scale to the (q,nlo) compute layout. f_y stays a
// per-lane gather (it is q-dependent, already duplicate-free).
// COMPUTE phase: lane (q,nlo) builds h for j = ch*32+q*8+jj (MFMA B-frag
// slots); C' = W2^T x h^T with acc preloaded with b2; col = own neighbor ->
// lane-local f*s epilogue, DPP row-sum, lane15 stores.
__global__ __launch_bounds__(256) void it_kernel(
    const float* __restrict__ y,
    const float* __restrict__ x,
    const float* __restrict__ f_y,
    const float* __restrict__ weights,
    const float* __restrict__ W1,   // [4][64] row-major
    const float* __restrict__ b1,   // [64]
    const float* __restrict__ W2,   // [64][16] row-major
    const float* __restrict__ b2,   // [16]
    const int*   __restrict__ nbr,  // [B][M][K] int32
    float*       __restrict__ out)  // [B][M][16]
{
    const int tid  = threadIdx.x;
    const int lane = tid & 63;
    const int q    = lane >> 4;    // quad 0..3
    const int nlo  = lane & 15;    // neighbor-within-half; also c for W2 A-frag
    const int wave = blockIdx.x * 4 + (tid >> 6);
    const int row0 = wave * RPW;           // both rows share the same batch b
    const int b    = row0 >> 12;           // M = 4096
    const int bbase = b * N_;

    // ---- dedup gather: lane g covers (row g>>5, neighbor g&31) ----
    const int r_g = lane >> 5, kk = lane & 31;
    const int raw = nbr[(size_t)(row0 + r_g) * K_ + kk];
    const int vld = raw >= 0;
    const int bn_g = bbase + (vld ? raw : 0);
    const float2 yvg = *(const float2*)(y + (size_t)bn_g * 2);
    const float  wg  = vld ? weights[bn_g] : 0.0f;

    // ---- redistribute to compute layout; issue f_y gathers early ----
    int   bn_ih[RPW][2];
    float s_ih[RPW][2];
    f32x2 yv_ih[RPW][2];
    floatx4 fv[RPW][2];
    #pragma unroll
    for (int it = 0; it < RPW; ++it)
        #pragma unroll
        for (int h = 0; h < 2; ++h) {
            const int src = ((it << 5) + (h << 4) + nlo) << 2;
            bn_ih[it][h] = bpermi(src, bn_g);
            fv[it][h] = *(const floatx4*)(f_y + (size_t)bn_ih[it][h] * 16 + q * 4);
            s_ih[it][h] = bpermf(src, wg);
            yv_ih[it][h][0] = bpermf(src, yvg.x);
            yv_ih[it][h][1] = bpermf(src, yvg.y);
        }

    float2 xv[RPW];
    #pragma unroll
    for (int it = 0; it < RPW; ++it)
        xv[it] = *(const float2*)(x + (size_t)(row0 + it) * 2);

    // ---- per-lane W1/b1 register slices (float2-packed) ----
    f32x2 w1r[2][4][4];   // [chunk][input dim][jj pair]
    f32x2 b1r[2][4];
    #pragma unroll
    for (int ch = 0; ch < 2; ++ch) {
        #pragma unroll
        for (int i = 0; i < 4; ++i) {
            const floatx4 a0 = *(const floatx4*)(W1 + i*64 + ch*32 + q*8);
            const floatx4 a1 = *(const floatx4*)(W1 + i*64 + ch*32 + q*8 + 4);
            w1r[ch][i][0] = (f32x2){a0[0], a0[1]};
            w1r[ch][i][1] = (f32x2){a0[2], a0[3]};
            w1r[ch][i][2] = (f32x2){a1[0], a1[1]};
            w1r[ch][i][3] = (f32x2){a1[2], a1[3]};
        }
        const floatx4 c0 = *(const floatx4*)(b1 + ch*32 + q*8);
        const floatx4 c1 = *(const floatx4*)(b1 + ch*32 + q*8 + 4);
        b1r[ch][0] = (f32x2){c0[0], c0[1]};
        b1r[ch][1] = (f32x2){c0[2], c0[3]};
        b1r[ch][2] = (f32x2){c1[0], c1[1]};
        b1r[ch][3] = (f32x2){c1[2], c1[3]};
    }

    // ---- W2 A-fragment: lane holds A[m=c=nlo][k=q*8+jj] = W2[j][nlo], bf16 ----
    short8 w2f[2];
    #pragma unroll
    for (int ch = 0; ch < 2; ++ch)
        #pragma unroll
        for (int jj = 0; jj < 8; ++jj)
            w2f[ch][jj] = f2bf(W2[(ch*32 + q*8 + jj) * DOUT_ + nlo]);

    const floatx4 b2v = *(const floatx4*)(b2 + q*4);

    #pragma unroll
    for (int it = 0; it < RPW; ++it) {
        const int row = row0 + it;
        float partial[4] = {0.f, 0.f, 0.f, 0.f};
        #pragma unroll
        for (int h = 0; h < 2; ++h) {
            short8 hf[2];
            #pragma unroll
            for (int ch = 0; ch < 2; ++ch) {
                #pragma unroll
                for (int p = 0; p < 4; ++p) {
                    f32x2 hin = b1r[ch][p];
                    hin = __builtin_elementwise_fma(splat2(yv_ih[it][h][0]), w1r[ch][0][p], hin);
                    hin = __builtin_elementwise_fma(splat2(yv_ih[it][h][1]), w1r[ch][1][p], hin);
                    hin = __builtin_elementwise_fma(splat2(xv[it].x),        w1r[ch][2][p], hin);
                    hin = __builtin_elementwise_fma(splat2(xv[it].y),        w1r[ch][3][p], hin);
                    const f32x2 g = gelu2(hin);
                    hf[ch][2*p]     = f2bf(g[0]);
                    hf[ch][2*p + 1] = f2bf(g[1]);
                }
            }
            // acc preloaded with b2 (broadcast across cols = neighbors)
            floatx4 acc = b2v;
            acc = __builtin_amdgcn_mfma_f32_16x16x32_bf16(w2f[0], hf[0], acc, 0, 0, 0);
            acc = __builtin_amdgcn_mfma_f32_16x16x32_bf16(w2f[1], hf[1], acc, 0, 0, 0);
            #pragma unroll
            for (int r4 = 0; r4 < 4; ++r4)
                partial[r4] = fmaf(acc[r4], fv[it][h][r4] * s_ih[it][h], partial[r4]);
        }

        // ---- sum over the 16 neighbors via DPP row_shr tree ----
        #pragma unroll
        for (int r4 = 0; r4 < 4; ++r4)
            partial[r4] = row16_sum(partial[r4]);

        if (nlo == 15) {
            floatx4 o = {partial[0], partial[1], partial[2], partial[3]};
            *(floatx4*)(out + (size_t)row * DOUT_ + q*4) = o;
        }
    }
}

extern "C" void kernel_launch(void* const* d_in, const int* in_sizes, int n_in,
                              void* d_out, int out_size, void* d_ws, size_t ws_size,
                              hipStream_t stream) {
    const float* y   = (const float*)d_in[0];
    const float* x   = (const float*)d_in[1];
    const float* f_y = (const float*)d_in[2];
    const float* w   = (const float*)d_in[3];
    const float* W1  = (const float*)d_in[4];
    const float* b1  = (const float*)d_in[5];
    const float* W2  = (const float*)d_in[6];
    const float* b2  = (const float*)d_in[7];
    const int*   nbr = (const int*)d_in[8];
    float* out = (float*)d_out;

    // 32768 rows / (4 waves * RPW rows) = 4096 blocks
    dim3 grid(B_ * M_ / (4 * RPW)), block(256);
    hipLaunchKernelGGL(it_kernel, grid, block, 0, stream,
                       y, x, f_y, w, W1, b1, W2, b2, nbr, out);
}